// Round 6
// baseline (10487.685 us; speedup 1.0000x reference)
//
#include <hip/hip_runtime.h>
#include <hip/hip_bf16.h>

#define NT 512
typedef unsigned short u16;

__device__ __forceinline__ u16 tobf(float x) {
  union { __hip_bfloat16 h; u16 u; } cv;
  cv.h = __float2bfloat16(x);
  return cv.u;
}
__device__ __forceinline__ float frombf(u16 u) {
  return __uint_as_float(((unsigned)u) << 16);
}
__device__ __forceinline__ float sigf(float x) {
  return __builtin_amdgcn_rcpf(1.f + __builtin_amdgcn_exp2f(-1.4426950408889634f * x));
}
__device__ __forceinline__ float tanh_fast(float x) {
  return 1.f - 2.f * __builtin_amdgcn_rcpf(1.f + __builtin_amdgcn_exp2f(2.8853900817779268f * x));
}

struct SeqArgs {
  const float* input;
  const float* nv1_0; const float* nv2_0; const float* nv1_1; const float* nv2_1;
  const float* w_start0; const float* b_start0; const float* w_mlp0; const float* b_mlp0;
  const float* w_end0;   const float* b_end0;   const float* w_lin0; const float* b_lin0;
  const float* gamma0;   const float* beta0;
  const float* w_start1; const float* b_start1; const float* w_mlp1; const float* b_mlp1;
  const float* w_end1;   const float* b_end1;   const float* w_lin1; const float* b_lin1;
  const float* gamma1;   const float* beta1;
  float* HCOL;   // ws ring [32][192][192] fp32
  int*   flags;  // ws [192*32] ints, stride 32 (128B)
  float* out_all; float* out_hrow; float* out_hcol;
};

__global__ __launch_bounds__(NT, 1) void seq_kernel(SeqArgs A) {
  const int n = blockIdx.x, w = n >> 3, b = n & 7, tid = threadIdx.x;
  const int pred = (n + 184) % 192;

  __shared__ __align__(16) float sCIN[768];     // [h_row | h_col | x(<=2ch)]
  __shared__ __align__(16) u16   sWS[64 * 132]; // conv weights bf16
  __shared__ __align__(16) float sAT[4096];     // aT[w*64+v]
  __shared__ __align__(16) float sH[2][1024];   // [c*64+v]; sH[1][0..14) stats, [32..224) hcn
  __shared__ __align__(16) float sAbuf[4928];
  float* const sG   = sAbuf;          // [0..2047]
  float* const sY   = sAbuf;          // [0..1151] (after sG dead)
  float* const sE   = sAbuf + 2048;   // 384
  float* const smWE = sAbuf + 3072;   // 192
  float* const smBE = sAbuf + 3264;   // 6
  float* const smWM = sAbuf + 3328;   // 32*50

  // thread roles
  const int c_cv = tid >> 5;                 // conv: channel-row 0..15
  const int vj   = (tid & 31) * 2;           // conv: 2 outputs
  const int v_p  = tid & 63, cq2 = (tid >> 6) * 2;  // prop: 2 channels
  const int o_m  = tid >> 4, v4 = (tid & 15) * 4;   // mlp: 1 o, 4 v
  const int dY   = (tid < 384) ? (tid - ((tid >= 192) ? 192 : 0)) : 0;
  const int half = (tid >= 192);
  const int dRC  = (tid < 192) ? tid : ((tid >= 256 && tid < 448) ? tid - 256 : -1);

  for (int layer = 0; layer < 2; ++layer) {
    const int in_dim = 3 + layer;
    const int P = in_dim - 1;
    const float* nv1    = layer ? A.nv1_1    : A.nv1_0;
    const float* nv2    = layer ? A.nv2_1    : A.nv2_0;
    const float* wstart = layer ? A.w_start1 : A.w_start0;
    const float* bs     = layer ? A.b_start1 : A.b_start0;
    const float* wm     = layer ? A.w_mlp1   : A.w_mlp0;
    const float* bm     = layer ? A.b_mlp1   : A.b_mlp0;
    const float* we     = layer ? A.w_end1   : A.w_end0;
    const float* be     = layer ? A.b_end1   : A.b_end0;
    const float* wl     = layer ? A.w_lin1   : A.w_lin0;
    const float* bl     = layer ? A.b_lin1   : A.b_lin0;
    const float* gm     = layer ? A.gamma1   : A.gamma0;
    const float* bt     = layer ? A.beta1    : A.beta0;

    // ---- layer init ----
    for (int idx = tid; idx < 4096; idx += NT) {
      int v = idx >> 6, ww = idx & 63;
      float s = 0.f;
      for (int j = 0; j < 40; ++j) s = fmaf(nv1[v*40 + j], nv2[j*64 + ww], s);
      sAbuf[idx] = fmaxf(s, 0.f);
    }
    __syncthreads();
    if (tid < 64) {
      const int v = tid;
      float m = -1e30f;
      for (int ww = 0; ww < 64; ++ww) m = fmaxf(m, sAbuf[v*64 + ww]);
      float s = 0.f;
      for (int ww = 0; ww < 64; ++ww) { float e = expf(sAbuf[v*64 + ww] - m); sAbuf[v*64 + ww] = e; s += e; }
      float inv = 1.f / s, rs = 1.f;
      for (int ww = 0; ww < 64; ++ww) rs += sAbuf[v*64 + ww] * inv;
      float irs = 1.f / rs;
      for (int ww = 0; ww < 64; ++ww) {
        float a = sAbuf[v*64 + ww] * inv + ((ww == v) ? 1.f : 0.f);
        sAT[ww*64 + v] = a * irs;
      }
    }
    __syncthreads();
    for (int idx = tid; idx < 16*in_dim*132; idx += NT) {
      int row = idx / 132, k = idx - row*132;
      sWS[idx] = (k < 129) ? tobf(wstart[((row & 15)*in_dim + (row >> 4))*129 + k]) : (u16)0;
    }
    for (int idx = tid; idx < 1536; idx += NT) { int o = idx/48, c = idx - o*48; smWM[o*50 + c] = wm[idx]; }
    for (int idx = tid; idx < 192; idx += NT) smWE[idx] = we[idx];
    if (tid < 6) smBE[tid] = be[tid];
    for (int d = tid; d < 384; d += NT) sCIN[d] = 0.f;

    const float bmv = bm[o_m];
    const float bs_c = bs[c_cv];
    float blv = 0.f, gmv = 1.f, btv = 0.f;
    if (tid < 384) blv = bl[dY];
    if (dRC >= 0) { gmv = gm[dRC]; btv = bt[dRC]; }
    __syncthreads();

    // stage x(t) into sCIN[384..)
    auto stage_x = [&](int t) {
      if (layer == 0) {
        int o = t - w;
        if (o >= 0 && o < 48) {
          const float4* xr = (const float4*)(A.input + (((size_t)(b*24 + w)*48 + o)*192));
          for (int i4 = tid; i4 < 48; i4 += NT) *(float4*)&sCIN[384 + i4*4] = xr[i4];
        } else {
          for (int d = tid; d < 192; d += NT) sCIN[384 + d] = 0.f;
        }
      } else {
        const float4* xr = (const float4*)(A.out_all + ((size_t)n*71 + t)*384);
        for (int i4 = tid; i4 < 96; i4 += NT) *(float4*)&sCIN[384 + i4*4] = xr[i4];
      }
    };

    float acc0, acc1;  // conv accumulators (persist across phases)
    // conv of pre channels (h_row + x) into regs
    auto conv_pre = [&]() {
      float a0 = bs_c, a1 = bs_c;
      for (int p = 0; p < P; ++p) {
        const int ich = (p == 0) ? 0 : (p + 1);
        const float* xin = (p == 0) ? &sCIN[vj] : &sCIN[384 + (p-1)*192 + vj];
        const u16* wrow = &sWS[(ich*16 + c_cv)*132];
        float2 c0 = *(const float2*)xin;
        for (int k4 = 0; k4 < 128; k4 += 4) {
          ushort4 wu = *(const ushort4*)(wrow + k4);
          float w0 = frombf(wu.x), w1 = frombf(wu.y), w2 = frombf(wu.z), w3 = frombf(wu.w);
          float2 c1 = *(const float2*)(xin + k4 + 2);
          float2 n0 = *(const float2*)(xin + k4 + 4);
          a0 = fmaf(w0,c0.x, fmaf(w1,c0.y, fmaf(w2,c1.x, fmaf(w3,c1.y, a0))));
          a1 = fmaf(w0,c0.y, fmaf(w1,c1.x, fmaf(w2,c1.y, fmaf(w3,n0.x, a1))));
          c0 = n0;
        }
        float wk = frombf(wrow[128]);
        a0 = fmaf(wk, c0.x, a0);
        a1 = fmaf(wk, c0.y, a1);
      }
      acc0 = a0; acc1 = a1;
    };

    stage_x(0);
    __syncthreads();
    conv_pre();

    for (int t = 0; t < 71; ++t) {
      const int S = layer*71 + t;

      if (t > 0) {
        if (tid == 0) {
          while (__hip_atomic_load(&A.flags[pred*32], __ATOMIC_ACQUIRE, __HIP_MEMORY_SCOPE_AGENT) < S)
            __builtin_amdgcn_s_sleep(1);
        }
        __syncthreads();  // B1
        float* hc = A.HCOL + ((size_t)((S-1) & 31)*192 + pred)*192;
        for (int d = tid; d < 192; d += NT)
          sCIN[192 + d] = __hip_atomic_load(&hc[d], __ATOMIC_RELAXED, __HIP_MEMORY_SCOPE_AGENT);
        __syncthreads();  // B2

        // h_col conv accumulate into regs
        {
          const float* xin = &sCIN[192 + vj];
          const u16* wrow = &sWS[(16 + c_cv)*132];
          float a0 = acc0, a1 = acc1;
          float2 c0 = *(const float2*)xin;
          for (int k4 = 0; k4 < 128; k4 += 4) {
            ushort4 wu = *(const ushort4*)(wrow + k4);
            float w0 = frombf(wu.x), w1 = frombf(wu.y), w2 = frombf(wu.z), w3 = frombf(wu.w);
            float2 c1 = *(const float2*)(xin + k4 + 2);
            float2 n0 = *(const float2*)(xin + k4 + 4);
            a0 = fmaf(w0,c0.x, fmaf(w1,c0.y, fmaf(w2,c1.x, fmaf(w3,c1.y, a0))));
            a1 = fmaf(w0,c0.y, fmaf(w1,c1.x, fmaf(w2,c1.y, fmaf(w3,n0.x, a1))));
            c0 = n0;
          }
          float wk = frombf(wrow[128]);
          a0 = fmaf(wk, c0.x, a0);
          a1 = fmaf(wk, c0.y, a1);
          *(float2*)&sH[0][c_cv*64 + vj] = make_float2(a0, a1);
        }
      } else {
        *(float2*)&sH[0][c_cv*64 + vj] = make_float2(acc0, acc1);
      }
      __syncthreads();  // B3

      float g[4];
      // (e) h1 = 0.05 h0 + 0.95 h0@aT -> sH[1]; G += wm[:,0:16] h0
      {
        g[0] = bmv; g[1] = bmv; g[2] = bmv; g[3] = bmv;
        float pa0 = 0.f, pa1 = 0.f;
        for (int w4 = 0; w4 < 64; w4 += 4) {
          float a0 = sAT[(w4+0)*64 + v_p];
          float a1 = sAT[(w4+1)*64 + v_p];
          float a2 = sAT[(w4+2)*64 + v_p];
          float a3 = sAT[(w4+3)*64 + v_p];
          float4 h0 = *(const float4*)&sH[0][cq2*64 + w4];
          float4 h1 = *(const float4*)&sH[0][(cq2+1)*64 + w4];
          pa0 = fmaf(h0.x,a0, fmaf(h0.y,a1, fmaf(h0.z,a2, fmaf(h0.w,a3, pa0))));
          pa1 = fmaf(h1.x,a0, fmaf(h1.y,a1, fmaf(h1.z,a2, fmaf(h1.w,a3, pa1))));
        }
        sH[1][cq2*64 + v_p]     = fmaf(0.95f, pa0, 0.05f*sH[0][cq2*64 + v_p]);
        sH[1][(cq2+1)*64 + v_p] = fmaf(0.95f, pa1, 0.05f*sH[0][(cq2+1)*64 + v_p]);
        for (int c = 0; c < 16; ++c) {
          float wv = smWM[o_m*50 + c];
          float4 hh = *(const float4*)&sH[0][c*64 + v4];
          g[0]=fmaf(wv,hh.x,g[0]); g[1]=fmaf(wv,hh.y,g[1]); g[2]=fmaf(wv,hh.z,g[2]); g[3]=fmaf(wv,hh.w,g[3]);
        }
      }
      __syncthreads();  // B4

      // (f) h2 = 0.05 h0 + 0.95 h1@aT in place; G += wm[:,16:32] h1
      {
        float pa0 = 0.f, pa1 = 0.f;
        for (int w4 = 0; w4 < 64; w4 += 4) {
          float a0 = sAT[(w4+0)*64 + v_p];
          float a1 = sAT[(w4+1)*64 + v_p];
          float a2 = sAT[(w4+2)*64 + v_p];
          float a3 = sAT[(w4+3)*64 + v_p];
          float4 h0 = *(const float4*)&sH[1][cq2*64 + w4];
          float4 h1 = *(const float4*)&sH[1][(cq2+1)*64 + w4];
          pa0 = fmaf(h0.x,a0, fmaf(h0.y,a1, fmaf(h0.z,a2, fmaf(h0.w,a3, pa0))));
          pa1 = fmaf(h1.x,a0, fmaf(h1.y,a1, fmaf(h1.z,a2, fmaf(h1.w,a3, pa1))));
        }
        float h00 = sH[0][cq2*64 + v_p], h01 = sH[0][(cq2+1)*64 + v_p];
        sH[0][cq2*64 + v_p]     = fmaf(0.95f, pa0, 0.05f*h00);
        sH[0][(cq2+1)*64 + v_p] = fmaf(0.95f, pa1, 0.05f*h01);
        for (int c = 0; c < 16; ++c) {
          float wv = smWM[o_m*50 + 16 + c];
          float4 hh = *(const float4*)&sH[1][c*64 + v4];
          g[0]=fmaf(wv,hh.x,g[0]); g[1]=fmaf(wv,hh.y,g[1]); g[2]=fmaf(wv,hh.z,g[2]); g[3]=fmaf(wv,hh.w,g[3]);
        }
      }
      __syncthreads();  // B5

      // (g) G += wm[:,32:48] h2; exact GELU -> sG
      {
        for (int c = 0; c < 16; ++c) {
          float wv = smWM[o_m*50 + 32 + c];
          float4 hh = *(const float4*)&sH[0][c*64 + v4];
          g[0]=fmaf(wv,hh.x,g[0]); g[1]=fmaf(wv,hh.y,g[1]); g[2]=fmaf(wv,hh.z,g[2]); g[3]=fmaf(wv,hh.w,g[3]);
        }
#pragma unroll
        for (int j = 0; j < 4; ++j) {
          float x = g[j];
          g[j] = 0.5f * x * (1.f + erff(x * 0.70710678118654752f));
        }
        *(float4*)&sG[o_m*64 + v4] = make_float4(g[0], g[1], g[2], g[3]);
      }
      __syncthreads();  // B6

      // (h) E = be + we @ G (384 threads, single pass)
      if (tid < 384) {
        int o2 = tid >> 6, v = tid & 63;
        float acc = smBE[o2];
        for (int c = 0; c < 32; ++c) acc = fmaf(smWE[o2*32 + c], sG[c*64 + v], acc);
        sE[tid] = acc;
      }
      __syncthreads();  // B7

      // (i) Y = bl + E @ wl^T (384 threads: 3 rows each)
      if (tid < 384) {
        const float4* wrow = (const float4*)(wl + dY*64);
        const float* sEb = sE + half*192;
        float y0 = blv, y1 = blv, y2 = blv;
        for (int q = 0; q < 16; ++q) {
          float4 wv = wrow[q];
          float4 e0 = *(const float4*)&sEb[0*64 + q*4];
          float4 e1 = *(const float4*)&sEb[1*64 + q*4];
          float4 e2 = *(const float4*)&sEb[2*64 + q*4];
          y0 = fmaf(e0.x,wv.x, fmaf(e0.y,wv.y, fmaf(e0.z,wv.z, fmaf(e0.w,wv.w, y0))));
          y1 = fmaf(e1.x,wv.x, fmaf(e1.y,wv.y, fmaf(e1.z,wv.z, fmaf(e1.w,wv.w, y1))));
          y2 = fmaf(e2.x,wv.x, fmaf(e2.y,wv.y, fmaf(e2.z,wv.z, fmaf(e2.w,wv.w, y2))));
        }
        sY[(half*3 + 0)*192 + dY] = y0;
        sY[(half*3 + 1)*192 + dY] = y1;
        sY[(half*3 + 2)*192 + dY] = y2;
      }
      __syncthreads();  // B8

      // (j) LN stats: wave r reduces row r
      if (tid < 384) {
        int r = tid >> 6, l = tid & 63;
        float sm = 0.f, sq = 0.f;
#pragma unroll
        for (int m2 = 0; m2 < 3; ++m2) {
          float v = sY[r*192 + l + 64*m2];
          sm += v; sq = fmaf(v, v, sq);
        }
#pragma unroll
        for (int off = 32; off >= 1; off >>= 1) {
          sm += __shfl_xor(sm, off);
          sq += __shfl_xor(sq, off);
        }
        if (l == 0) {
          float mu = sm * (1.f/192.f);
          float var = sq * (1.f/192.f) - mu*mu;
          sH[1][r] = mu;
          sH[1][8 + r] = rsqrtf(fmaxf(var, 0.f) + 1e-5f);
        }
      }
      __syncthreads();  // B9

      // (k) col gates (waves 0-2) || row gates (waves 4-6)
      float hrn = 0.f, rx0 = 0.f, rx1 = 0.f;
      if (tid < 192) {
        const int d = tid;
        float y2 = fmaf((sY[384 + d] - sH[1][2]) * sH[1][10], gmv, btv);
        float y3 = fmaf((sY[576 + d] - sH[1][3]) * sH[1][11], gmv, btv);
        float y5 = fmaf((sY[960 + d] - sH[1][5]) * sH[1][13], gmv, btv);
        float ugc = sigf(y2), ogc = sigf(y3), igc = tanh_fast(y5);
        float hc = sCIN[192 + d];
        float hcn = tanh_fast(fmaf(ugc, igc, (1.f - ugc)*hc)) * ogc;
        sH[1][32 + d] = hcn;
        __hip_atomic_store(&A.HCOL[((size_t)(S & 31)*192 + n)*192 + d], hcn,
                           __ATOMIC_RELAXED, __HIP_MEMORY_SCOPE_AGENT);
      } else if (dRC >= 0) {
        const int d = dRC;
        float y0 = fmaf((sY[d]       - sH[1][0]) * sH[1][8],  gmv, btv);
        float y1 = fmaf((sY[192 + d] - sH[1][1]) * sH[1][9],  gmv, btv);
        float y4 = fmaf((sY[768 + d] - sH[1][4]) * sH[1][12], gmv, btv);
        float ugr = sigf(y0), ogr = sigf(y1), igr = tanh_fast(y4);
        float hr = sCIN[d];
        hrn = tanh_fast(fmaf(ugr, igr, (1.f - ugr)*hr)) * ogr;
        sCIN[d] = hrn;
        if (layer) { rx0 = sCIN[384 + d]; rx1 = sCIN[576 + d]; }
      }
      __syncthreads();  // B10

      if (tid == 0) {
        __threadfence();
        __hip_atomic_store(&A.flags[n*32], S + 1, __ATOMIC_RELEASE, __HIP_MEMORY_SCOPE_AGENT);
      }
      if (tid >= 256 && tid < 448) {
        const int d = dRC;
        float hcn = sH[1][32 + d];
        float* oa = A.out_all + ((size_t)n*71 + t)*384;
        if (layer == 0) { oa[d] = hrn; oa[192 + d] = hcn; }
        else            { oa[d] = hrn + rx0; oa[192 + d] = hcn + rx1; }
        if (t == 47 + w)
          A.out_hrow[(((size_t)b*2 + layer)*24 + w)*192 + d] = hrn;
        if (w == 23 && t >= 23)
          A.out_hcol[(((size_t)b*2 + layer)*48 + (t - 23))*192 + d] = hcn;
      }
      if (t < 70) {
        stage_x(t + 1);
        __syncthreads();  // Bpre
        conv_pre();
      }
    } // t
    __syncthreads();
  } // layer
}

extern "C" void kernel_launch(void* const* d_in, const int* in_sizes, int n_in,
                              void* d_out, int out_size, void* d_ws, size_t ws_size,
                              hipStream_t stream) {
  (void)in_sizes; (void)n_in; (void)out_size; (void)ws_size;
  char* ws = (char*)d_ws;
  int*   flags = (int*)ws;                 // 24,576 B
  float* HCOL  = (float*)(ws + 24576);     // 4,718,592 B

  hipMemsetAsync(flags, 0, 24576, stream);

  SeqArgs A;
  A.input    = (const float*)d_in[0];
  A.nv1_0    = (const float*)d_in[1];  A.nv2_0 = (const float*)d_in[2];
  A.w_start0 = (const float*)d_in[3];  A.b_start0 = (const float*)d_in[4];
  A.w_mlp0   = (const float*)d_in[5];  A.b_mlp0   = (const float*)d_in[6];
  A.w_end0   = (const float*)d_in[7];  A.b_end0   = (const float*)d_in[8];
  A.w_lin0   = (const float*)d_in[9];  A.b_lin0   = (const float*)d_in[10];
  A.gamma0   = (const float*)d_in[11]; A.beta0    = (const float*)d_in[12];
  A.nv1_1    = (const float*)d_in[13]; A.nv2_1 = (const float*)d_in[14];
  A.w_start1 = (const float*)d_in[15]; A.b_start1 = (const float*)d_in[16];
  A.w_mlp1   = (const float*)d_in[17]; A.b_mlp1   = (const float*)d_in[18];
  A.w_end1   = (const float*)d_in[19]; A.b_end1   = (const float*)d_in[20];
  A.w_lin1   = (const float*)d_in[21]; A.b_lin1   = (const float*)d_in[22];
  A.gamma1   = (const float*)d_in[23]; A.beta1    = (const float*)d_in[24];
  A.HCOL = HCOL; A.flags = flags;
  A.out_all  = (float*)d_out;
  A.out_hrow = (float*)d_out + 5234688;
  A.out_hcol = (float*)d_out + 5308416;

  seq_kernel<<<192, NT, 0, stream>>>(A);
}

// Round 7
// 10005.006 us; speedup vs baseline: 1.0482x; 1.0482x over previous
//
#include <hip/hip_runtime.h>
#include <hip/hip_bf16.h>

#define NT 256
typedef unsigned short u16;

__device__ __forceinline__ u16 tobf(float x) {
  union { __hip_bfloat16 h; u16 u; } cv;
  cv.h = __float2bfloat16(x);
  return cv.u;
}
__device__ __forceinline__ float frombf(u16 u) {
  return __uint_as_float(((unsigned)u) << 16);
}
__device__ __forceinline__ float sigf(float x) {
  return __builtin_amdgcn_rcpf(1.f + __builtin_amdgcn_exp2f(-1.4426950408889634f * x));
}
__device__ __forceinline__ float tanh_fast(float x) {
  return 1.f - 2.f * __builtin_amdgcn_rcpf(1.f + __builtin_amdgcn_exp2f(2.8853900817779268f * x));
}

struct SeqArgs {
  const float* input;
  const float* nv1_0; const float* nv2_0; const float* nv1_1; const float* nv2_1;
  const float* w_start0; const float* b_start0; const float* w_mlp0; const float* b_mlp0;
  const float* w_end0;   const float* b_end0;   const float* w_lin0; const float* b_lin0;
  const float* gamma0;   const float* beta0;
  const float* w_start1; const float* b_start1; const float* w_mlp1; const float* b_mlp1;
  const float* w_end1;   const float* b_end1;   const float* w_lin1; const float* b_lin1;
  const float* gamma1;   const float* beta1;
  float* HCOL;   // ws: per-layer rings [2][32][192][192] fp32
  int*   flags;  // ws: [192*32] ints; [n*32]=flagC0, [n*32+8]=flagC1, [n*32+16]=flagX
  float* out_all; float* out_hrow; float* out_hcol;
};

// Block = (n, layer): 384 blocks. Layer 1 pipelines ~2 steps behind layer 0.
__global__ __launch_bounds__(NT, 2) void seq_kernel(SeqArgs A) {
  const int bid = blockIdx.x;
  const int layer = bid & 1;
  const int n = bid >> 1;
  const int w = n >> 3, b = n & 7, tid = threadIdx.x;
  const int pred = (n + 184) % 192;

  __shared__ __align__(16) float sCIN[768];     // [h_row | h_col | x(<=2ch)]
  __shared__ __align__(16) u16   sWS[64 * 132]; // conv weights bf16
  __shared__ __align__(16) float sAT[4096];     // aT[w*64+v]
  __shared__ __align__(16) float sH[2][1024];   // [c*64+v]; sH[1][0..14) also LN stats
  __shared__ __align__(16) float sAbuf[4928];
  float* const sPart = sAbuf;          // pre-conv partials (P*16*64)
  float* const sG    = sAbuf;          // [0..2047]
  float* const sE    = sAbuf + 2048;   // 384
  float* const sY    = sAbuf;          // [0..1151]
  float* const smWE  = sAbuf + 3072;   // 192
  float* const smBE  = sAbuf + 3264;   // 6
  float* const smWM  = sAbuf + 3328;   // 32*50

  const int in_dim = 3 + layer;
  const int P = in_dim - 1;
  const float* nv1    = layer ? A.nv1_1    : A.nv1_0;
  const float* nv2    = layer ? A.nv2_1    : A.nv2_0;
  const float* wstart = layer ? A.w_start1 : A.w_start0;
  const float* bs     = layer ? A.b_start1 : A.b_start0;
  const float* wm     = layer ? A.w_mlp1   : A.w_mlp0;
  const float* bm     = layer ? A.b_mlp1   : A.b_mlp0;
  const float* we     = layer ? A.w_end1   : A.w_end0;
  const float* be     = layer ? A.b_end1   : A.b_end0;
  const float* wl     = layer ? A.w_lin1   : A.w_lin0;
  const float* bl     = layer ? A.b_lin1   : A.b_lin0;
  const float* gm     = layer ? A.gamma1   : A.gamma0;
  const float* bt     = layer ? A.beta1    : A.beta0;
  float* const HCOL   = A.HCOL + (size_t)layer * 1179648;  // 32*192*192
  int* const  flagC_o = &A.flags[n*32 + layer*8];
  int* const  flagC_p = &A.flags[pred*32 + layer*8];
  int* const  flagX   = &A.flags[n*32 + 16];

  // ---- init: adjacency (scores -> softmax -> sAT), weights, regs ----
  for (int idx = tid; idx < 4096; idx += NT) {
    int v = idx >> 6, ww = idx & 63;
    float s = 0.f;
    for (int j = 0; j < 40; ++j) s = fmaf(nv1[v*40 + j], nv2[j*64 + ww], s);
    sAbuf[idx] = fmaxf(s, 0.f);
  }
  __syncthreads();
  if (tid < 64) {
    const int v = tid;
    float m = -1e30f;
    for (int ww = 0; ww < 64; ++ww) m = fmaxf(m, sAbuf[v*64 + ww]);
    float s = 0.f;
    for (int ww = 0; ww < 64; ++ww) { float e = expf(sAbuf[v*64 + ww] - m); sAbuf[v*64 + ww] = e; s += e; }
    float inv = 1.f / s, rs = 1.f;
    for (int ww = 0; ww < 64; ++ww) rs += sAbuf[v*64 + ww] * inv;
    float irs = 1.f / rs;
    for (int ww = 0; ww < 64; ++ww) {
      float a = sAbuf[v*64 + ww] * inv + ((ww == v) ? 1.f : 0.f);
      sAT[ww*64 + v] = a * irs;
    }
  }
  __syncthreads();
  for (int idx = tid; idx < 16*in_dim*132; idx += NT) {
    int row = idx / 132, k = idx - row*132;
    sWS[idx] = (k < 129) ? tobf(wstart[((row & 15)*in_dim + (row >> 4))*129 + k]) : (u16)0;
  }
  for (int idx = tid; idx < 1536; idx += NT) { int o = idx/48, c = idx - o*48; smWM[o*50 + c] = wm[idx]; }
  for (int idx = tid; idx < 192; idx += NT) smWE[idx] = we[idx];
  if (tid < 6) smBE[tid] = be[tid];
  for (int d = tid; d < 384; d += NT) sCIN[d] = 0.f;

  const int o_m = tid >> 3, v8 = (tid & 7)*8;
  const int v_p = tid & 63, cq = tid >> 6;
  const float bmv = bm[o_m];
  float blv = 0.f, gmv = 1.f, btv = 0.f;
  if (tid < 192) { blv = bl[tid]; gmv = gm[tid]; btv = bt[tid]; }
  float bs_r[4];
#pragma unroll
  for (int m = 0; m < 4; ++m) bs_r[m] = bs[(tid >> 6) + 4*m];
  __syncthreads();

  // ---- pre-phase: stage x(t), conv of {h_row, x} channels, assemble h0pre ----
  auto pre_phase = [&](int t) {
    if (layer == 0) {
      int o = t - w;
      if (o >= 0 && o < 48) {
        const float* xr = A.input + (((size_t)(b*24 + w)*48 + o)*192);
        for (int d = tid; d < 192; d += NT) sCIN[384 + d] = xr[d];
      } else {
        for (int d = tid; d < 192; d += NT) sCIN[384 + d] = 0.f;
      }
    } else {
      // wait for layer-0 row n step t output, then read (agent-scope)
      if (tid == 0) {
        while (__hip_atomic_load(flagX, __ATOMIC_ACQUIRE, __HIP_MEMORY_SCOPE_AGENT) < t + 1)
          __builtin_amdgcn_s_sleep(1);
      }
      __syncthreads();
      const float* xr = A.out_all + ((size_t)n*71 + t)*384;
      for (int d = tid; d < 384; d += NT)
        sCIN[384 + d] = __hip_atomic_load(&xr[d], __ATOMIC_RELAXED, __HIP_MEMORY_SCOPE_AGENT);
    }
    __syncthreads();
    {
      const int ci = tid >> 2, vq = tid & 3;
      const int p = ci >> 4, c = ci & 15;
      if (p < P) {
        const int ich = (p == 0) ? 0 : (p + 1);
        float acc[16];
#pragma unroll
        for (int j = 0; j < 16; ++j) acc[j] = 0.f;
        const float* xin = (p == 0) ? &sCIN[vq*16] : &sCIN[384 + (p-1)*192 + vq*16];
        const u16* wrow = &sWS[(ich*16 + c)*132];
        for (int k4 = 0; k4 < 128; k4 += 4) {
          ushort4 wu = *(const ushort4*)(wrow + k4);
          float w0 = frombf(wu.x), w1 = frombf(wu.y), w2 = frombf(wu.z), w3 = frombf(wu.w);
          union { float4 v4[5]; float f[20]; } X;
#pragma unroll
          for (int m = 0; m < 5; ++m) X.v4[m] = *(const float4*)(xin + k4 + 4*m);
#pragma unroll
          for (int j = 0; j < 16; ++j) {
            acc[j] = fmaf(w0, X.f[j],   acc[j]);
            acc[j] = fmaf(w1, X.f[j+1], acc[j]);
            acc[j] = fmaf(w2, X.f[j+2], acc[j]);
            acc[j] = fmaf(w3, X.f[j+3], acc[j]);
          }
        }
        {
          float wk = frombf(wrow[128]);
          union { float4 v4[4]; float f[16]; } X;
#pragma unroll
          for (int m = 0; m < 4; ++m) X.v4[m] = *(const float4*)(xin + 128 + 4*m);
#pragma unroll
          for (int j = 0; j < 16; ++j) acc[j] = fmaf(wk, X.f[j], acc[j]);
        }
        float* pp = &sPart[(p*16 + c)*64 + vq*16];
#pragma unroll
        for (int m = 0; m < 4; ++m)
          *(float4*)(pp + 4*m) = make_float4(acc[4*m], acc[4*m+1], acc[4*m+2], acc[4*m+3]);
      }
    }
    __syncthreads();
    {
      int m = 0;
      for (int idx = tid; idx < 1024; idx += NT, ++m) {
        int c = idx >> 6, v = idx & 63;
        float s = bs_r[m];
        for (int p = 0; p < P; ++p) s += sPart[(p*16 + c)*64 + v];
        sH[0][idx] = s;
      }
    }
    __syncthreads();
  };
  pre_phase(0);

  for (int t = 0; t < 71; ++t) {
    // ---- dependent path ----
    if (t > 0) {
      if (tid == 0) {
        while (__hip_atomic_load(flagC_p, __ATOMIC_ACQUIRE, __HIP_MEMORY_SCOPE_AGENT) < t)
          __builtin_amdgcn_s_sleep(1);
      }
      __syncthreads();  // B1
      float* hc = HCOL + ((size_t)((t-1) & 31)*192 + pred)*192;
      for (int d = tid; d < 192; d += NT)
        sCIN[192 + d] = __hip_atomic_load(&hc[d], __ATOMIC_RELAXED, __HIP_MEMORY_SCOPE_AGENT);
      __syncthreads();  // B2
    }

    // h_col conv, in-place accumulate into sH[0] (thread owns (c, vg*4..+3))
    {
      const int c = tid >> 4, vg = tid & 15;
      const float* xin = &sCIN[192 + vg*4];
      const u16* wrow = &sWS[(16 + c)*132];
      float4 a4 = *(const float4*)&sH[0][c*64 + vg*4];
      float a0 = a4.x, a1 = a4.y, a2 = a4.z, a3 = a4.w;
      float4 xc = *(const float4*)xin;
      for (int k4 = 0; k4 < 128; k4 += 4) {
        ushort4 wu = *(const ushort4*)(wrow + k4);
        float w0 = frombf(wu.x), w1 = frombf(wu.y), w2 = frombf(wu.z), w3 = frombf(wu.w);
        float4 xn = *(const float4*)(xin + k4 + 4);
        a0 = fmaf(w3, xc.w, fmaf(w2, xc.z, fmaf(w1, xc.y, fmaf(w0, xc.x, a0))));
        a1 = fmaf(w3, xn.x, fmaf(w2, xc.w, fmaf(w1, xc.z, fmaf(w0, xc.y, a1))));
        a2 = fmaf(w3, xn.y, fmaf(w2, xn.x, fmaf(w1, xc.w, fmaf(w0, xc.z, a2))));
        a3 = fmaf(w3, xn.z, fmaf(w2, xn.y, fmaf(w1, xn.x, fmaf(w0, xc.w, a3))));
        xc = xn;
      }
      float wk = frombf(wrow[128]);
      a0 = fmaf(wk, xc.x, a0); a1 = fmaf(wk, xc.y, a1);
      a2 = fmaf(wk, xc.z, a2); a3 = fmaf(wk, xc.w, a3);
      *(float4*)&sH[0][c*64 + vg*4] = make_float4(a0, a1, a2, a3);
    }
    __syncthreads();  // B3

    float g[8];
    // (e) h1 = 0.05 h0 + 0.95 h0@aT -> sH[1]; G += wm[:,0:16] h0
    {
#pragma unroll
      for (int j = 0; j < 8; ++j) g[j] = bmv;
      float pa[4] = {0.f, 0.f, 0.f, 0.f};
      for (int w4 = 0; w4 < 64; w4 += 4) {
        float a0 = sAT[(w4+0)*64 + v_p];
        float a1 = sAT[(w4+1)*64 + v_p];
        float a2 = sAT[(w4+2)*64 + v_p];
        float a3 = sAT[(w4+3)*64 + v_p];
#pragma unroll
        for (int j = 0; j < 4; ++j) {
          float4 h = *(const float4*)&sH[0][(cq*4 + j)*64 + w4];
          pa[j] = fmaf(h.x, a0, pa[j]); pa[j] = fmaf(h.y, a1, pa[j]);
          pa[j] = fmaf(h.z, a2, pa[j]); pa[j] = fmaf(h.w, a3, pa[j]);
        }
      }
#pragma unroll
      for (int j = 0; j < 4; ++j) {
        int c = cq*4 + j;
        sH[1][c*64 + v_p] = fmaf(0.95f, pa[j], 0.05f*sH[0][c*64 + v_p]);
      }
      for (int c = 0; c < 16; ++c) {
        float wv = smWM[o_m*50 + c];
        float4 ha = *(const float4*)&sH[0][c*64 + v8];
        float4 hb = *(const float4*)&sH[0][c*64 + v8 + 4];
        g[0]=fmaf(wv,ha.x,g[0]); g[1]=fmaf(wv,ha.y,g[1]); g[2]=fmaf(wv,ha.z,g[2]); g[3]=fmaf(wv,ha.w,g[3]);
        g[4]=fmaf(wv,hb.x,g[4]); g[5]=fmaf(wv,hb.y,g[5]); g[6]=fmaf(wv,hb.z,g[6]); g[7]=fmaf(wv,hb.w,g[7]);
      }
    }
    __syncthreads();  // B4

    // (f) h2 = 0.05 h0 + 0.95 h1@aT in place; G += wm[:,16:32] h1
    {
      float pa[4] = {0.f, 0.f, 0.f, 0.f};
      for (int w4 = 0; w4 < 64; w4 += 4) {
        float a0 = sAT[(w4+0)*64 + v_p];
        float a1 = sAT[(w4+1)*64 + v_p];
        float a2 = sAT[(w4+2)*64 + v_p];
        float a3 = sAT[(w4+3)*64 + v_p];
#pragma unroll
        for (int j = 0; j < 4; ++j) {
          float4 h = *(const float4*)&sH[1][(cq*4 + j)*64 + w4];
          pa[j] = fmaf(h.x, a0, pa[j]); pa[j] = fmaf(h.y, a1, pa[j]);
          pa[j] = fmaf(h.z, a2, pa[j]); pa[j] = fmaf(h.w, a3, pa[j]);
        }
      }
#pragma unroll
      for (int j = 0; j < 4; ++j) {
        int c = cq*4 + j;
        float h0v = sH[0][c*64 + v_p];
        sH[0][c*64 + v_p] = fmaf(0.95f, pa[j], 0.05f*h0v);
      }
      for (int c = 0; c < 16; ++c) {
        float wv = smWM[o_m*50 + 16 + c];
        float4 ha = *(const float4*)&sH[1][c*64 + v8];
        float4 hb = *(const float4*)&sH[1][c*64 + v8 + 4];
        g[0]=fmaf(wv,ha.x,g[0]); g[1]=fmaf(wv,ha.y,g[1]); g[2]=fmaf(wv,ha.z,g[2]); g[3]=fmaf(wv,ha.w,g[3]);
        g[4]=fmaf(wv,hb.x,g[4]); g[5]=fmaf(wv,hb.y,g[5]); g[6]=fmaf(wv,hb.z,g[6]); g[7]=fmaf(wv,hb.w,g[7]);
      }
    }
    __syncthreads();  // B5

    // (g) G += wm[:,32:48] h2; exact GELU -> sG
    {
      for (int c = 0; c < 16; ++c) {
        float wv = smWM[o_m*50 + 32 + c];
        float4 ha = *(const float4*)&sH[0][c*64 + v8];
        float4 hb = *(const float4*)&sH[0][c*64 + v8 + 4];
        g[0]=fmaf(wv,ha.x,g[0]); g[1]=fmaf(wv,ha.y,g[1]); g[2]=fmaf(wv,ha.z,g[2]); g[3]=fmaf(wv,ha.w,g[3]);
        g[4]=fmaf(wv,hb.x,g[4]); g[5]=fmaf(wv,hb.y,g[5]); g[6]=fmaf(wv,hb.z,g[6]); g[7]=fmaf(wv,hb.w,g[7]);
      }
#pragma unroll
      for (int j = 0; j < 8; ++j) {
        float x = g[j];
        g[j] = 0.5f * x * (1.f + erff(x * 0.70710678118654752f));
      }
      *(float4*)&sG[o_m*64 + v8]     = make_float4(g[0], g[1], g[2], g[3]);
      *(float4*)&sG[o_m*64 + v8 + 4] = make_float4(g[4], g[5], g[6], g[7]);
    }
    __syncthreads();  // B6

    // (h) E = be + we @ G
    for (int idx = tid; idx < 384; idx += NT) {
      int o2 = idx >> 6, v = idx & 63;
      float acc = smBE[o2];
      for (int c = 0; c < 32; ++c) acc = fmaf(smWE[o2*32 + c], sG[c*64 + v], acc);
      sE[idx] = acc;
    }
    __syncthreads();  // B7

    // (i) Y = bl + E @ wl^T
    if (tid < 192) {
      const int d = tid;
      const float4* wrow = (const float4*)(wl + d*64);
      float y0=blv, y1=blv, y2=blv, y3=blv, y4=blv, y5=blv;
      for (int q = 0; q < 16; ++q) {
        float4 wv = wrow[q];
        float4 e0 = *(const float4*)&sE[0*64 + q*4];
        float4 e1 = *(const float4*)&sE[1*64 + q*4];
        float4 e2 = *(const float4*)&sE[2*64 + q*4];
        float4 e3 = *(const float4*)&sE[3*64 + q*4];
        float4 e4 = *(const float4*)&sE[4*64 + q*4];
        float4 e5 = *(const float4*)&sE[5*64 + q*4];
        y0 = fmaf(e0.x,wv.x, fmaf(e0.y,wv.y, fmaf(e0.z,wv.z, fmaf(e0.w,wv.w, y0))));
        y1 = fmaf(e1.x,wv.x, fmaf(e1.y,wv.y, fmaf(e1.z,wv.z, fmaf(e1.w,wv.w, y1))));
        y2 = fmaf(e2.x,wv.x, fmaf(e2.y,wv.y, fmaf(e2.z,wv.z, fmaf(e2.w,wv.w, y2))));
        y3 = fmaf(e3.x,wv.x, fmaf(e3.y,wv.y, fmaf(e3.z,wv.z, fmaf(e3.w,wv.w, y3))));
        y4 = fmaf(e4.x,wv.x, fmaf(e4.y,wv.y, fmaf(e4.z,wv.z, fmaf(e4.w,wv.w, y4))));
        y5 = fmaf(e5.x,wv.x, fmaf(e5.y,wv.y, fmaf(e5.z,wv.z, fmaf(e5.w,wv.w, y5))));
      }
      sY[0*192+d]=y0; sY[1*192+d]=y1; sY[2*192+d]=y2;
      sY[3*192+d]=y3; sY[4*192+d]=y4; sY[5*192+d]=y5;
    }
    __syncthreads();  // B8

    // (j) LN stats -> sH[1][0..13]
    if (tid < 192) {
      const int r = tid >> 5, l32 = tid & 31;
      float sm = 0.f, sq = 0.f;
#pragma unroll
      for (int m = 0; m < 6; ++m) {
        float v = sY[r*192 + l32 + 32*m];
        sm += v; sq = fmaf(v, v, sq);
      }
#pragma unroll
      for (int off = 16; off >= 1; off >>= 1) {
        sm += __shfl_xor(sm, off);
        sq += __shfl_xor(sq, off);
      }
      if (l32 == 0) {
        float mu = sm * (1.f/192.f);
        float var = sq * (1.f/192.f) - mu*mu;
        sH[1][r] = mu;
        sH[1][8 + r] = rsqrtf(fmaxf(var, 0.f) + 1e-5f);
      }
    }
    __syncthreads();  // B9

    float hcn = 0.f;
    // (k1) col gates -> hcn -> HCOL
    if (tid < 192) {
      const int d = tid;
      float y2 = fmaf((sY[2*192+d] - sH[1][2]) * sH[1][10], gmv, btv);
      float y3 = fmaf((sY[3*192+d] - sH[1][3]) * sH[1][11], gmv, btv);
      float y5 = fmaf((sY[5*192+d] - sH[1][5]) * sH[1][13], gmv, btv);
      float ugc = sigf(y2), ogc = sigf(y3), igc = tanh_fast(y5);
      float hc = sCIN[192 + d];
      hcn = tanh_fast(fmaf(ugc, igc, (1.f - ugc)*hc)) * ogc;
      __hip_atomic_store(&HCOL[((size_t)(t & 31)*192 + n)*192 + d], hcn,
                         __ATOMIC_RELAXED, __HIP_MEMORY_SCOPE_AGENT);
    }
    __syncthreads();  // B10
    if (tid == 0) {
      __threadfence();
      __hip_atomic_store(flagC_o, t + 1, __ATOMIC_RELEASE, __HIP_MEMORY_SCOPE_AGENT);
    }
    // (k2) row gates + outputs (off ring critical path)
    if (tid < 192) {
      const int d = tid;
      float y0 = fmaf((sY[0*192+d] - sH[1][0]) * sH[1][8],  gmv, btv);
      float y1 = fmaf((sY[1*192+d] - sH[1][1]) * sH[1][9],  gmv, btv);
      float y4 = fmaf((sY[4*192+d] - sH[1][4]) * sH[1][12], gmv, btv);
      float ugr = sigf(y0), ogr = sigf(y1), igr = tanh_fast(y4);
      float hr = sCIN[d];
      float hrn = tanh_fast(fmaf(ugr, igr, (1.f - ugr)*hr)) * ogr;
      sCIN[d] = hrn;
      float* oa = A.out_all + ((size_t)n*71 + t)*384;
      if (layer == 0) { oa[d] = hrn; oa[192 + d] = hcn; }
      else            { oa[d] = hrn + sCIN[384 + d]; oa[192 + d] = hcn + sCIN[576 + d]; }
      if (t == 47 + w)
        A.out_hrow[(((size_t)b*2 + layer)*24 + w)*192 + d] = hrn;
      if (w == 23 && t >= 23)
        A.out_hcol[(((size_t)b*2 + layer)*48 + (t - 23))*192 + d] = hcn;
    }
    __syncthreads();  // B11
    if (layer == 0 && tid == 0) {
      __threadfence();
      __hip_atomic_store(flagX, t + 1, __ATOMIC_RELEASE, __HIP_MEMORY_SCOPE_AGENT);
    }
    if (t < 70) pre_phase(t + 1);
  } // t
}

extern "C" void kernel_launch(void* const* d_in, const int* in_sizes, int n_in,
                              void* d_out, int out_size, void* d_ws, size_t ws_size,
                              hipStream_t stream) {
  (void)in_sizes; (void)n_in; (void)out_size; (void)ws_size;
  char* ws = (char*)d_ws;
  int*   flags = (int*)ws;                 // 24,576 B
  float* HCOL  = (float*)(ws + 24576);     // 2 x 4,718,592 B (per-layer ring-32)
  // total ws: 9,461,760 B

  hipMemsetAsync(flags, 0, 24576, stream);

  SeqArgs A;
  A.input    = (const float*)d_in[0];
  A.nv1_0    = (const float*)d_in[1];  A.nv2_0 = (const float*)d_in[2];
  A.w_start0 = (const float*)d_in[3];  A.b_start0 = (const float*)d_in[4];
  A.w_mlp0   = (const float*)d_in[5];  A.b_mlp0   = (const float*)d_in[6];
  A.w_end0   = (const float*)d_in[7];  A.b_end0   = (const float*)d_in[8];
  A.w_lin0   = (const float*)d_in[9];  A.b_lin0   = (const float*)d_in[10];
  A.gamma0   = (const float*)d_in[11]; A.beta0    = (const float*)d_in[12];
  A.nv1_1    = (const float*)d_in[13]; A.nv2_1 = (const float*)d_in[14];
  A.w_start1 = (const float*)d_in[15]; A.b_start1 = (const float*)d_in[16];
  A.w_mlp1   = (const float*)d_in[17]; A.b_mlp1   = (const float*)d_in[18];
  A.w_end1   = (const float*)d_in[19]; A.b_end1   = (const float*)d_in[20];
  A.w_lin1   = (const float*)d_in[21]; A.b_lin1   = (const float*)d_in[22];
  A.gamma1   = (const float*)d_in[23]; A.beta1    = (const float*)d_in[24];
  A.HCOL = HCOL; A.flags = flags;
  A.out_all  = (float*)d_out;
  A.out_hrow = (float*)d_out + 5234688;
  A.out_hcol = (float*)d_out + 5308416;

  seq_kernel<<<384, NT, 0, stream>>>(A);
}